// Round 3
// baseline (98.425 us; speedup 1.0000x reference)
//
#include <hip/hip_runtime.h>

#define HH 1200
#define WW 1920
#define HW (HH*WW)
#define MINC (1.0f/1048575.0f)
#define LOGMC (-13.862942657524135f)
#define CROP_N 576000   // 600 rows (1,3,..,1199) x 960 cols (0,2,..,1918)

// ---- workspace layout (bytes) ----
#define O_COARSE 0          // u32[4096]
#define O_FINE   16384      // u32[256]
#define O_HIST   17408      // u32[256]
#define O_INTS   18432      // i32[4]: 0=T 1=kprime 2=done
#define O_A2     18448      // f32[4096]
#define O_A3     34832      // f32[2048]
#define O_A4     43024      // f32[1024]
#define WS_TOTAL 47120
#define ZERO_U32 4612       // coarse+fine+hist+ints, zeroed every call by k_zero

__device__ __forceinline__ float merge3(float low, float mid, float high) {
    float lm = (mid == 4095.0f) ? low : 0.0f;
    float hm = (mid <= 255.0f) ? high : 0.0f;
    float mm = (mid >= 256.0f && mid <= 4094.0f) ? mid : 0.0f;
    return hm * (1.0f/256.0f) + mm * (1.0f/16.0f) + lm;
}

__device__ __forceinline__ int merged_q(const float* __restrict__ img, int idx) {
    float low  = rintf(img[idx] * 4095.0f);
    float mid  = rintf(img[idx + HW] * 4095.0f);
    float high = rintf(img[idx + 2*HW] * 4095.0f);
    float v = merge3(low, mid, high);
    return __float2int_rn(v * 256.0f);   // exact: v is a multiple of 1/256
}

// Per-block mask/rowlist rebuild (redundant across blocks; a few hundred cycles).
// colf[1920]: final col mask. rowlist[<=1200]: selected row indices (order-free).
// Returns nothing; counts in *s_nr, *s_nc.
__device__ __forceinline__ void build_masks(unsigned char* rawr, unsigned char* rawc,
                                            unsigned char* colf, short* rowlist,
                                            int* s_nr, int* s_nc) {
    int t = threadIdx.x;
    for (int i = t; i < HH; i += 256) rawr[i] = 0;
    for (int i = t; i < WW; i += 256) rawc[i] = 0;
    if (t == 0) { *s_nr = 0; *s_nc = 0; }
    __syncthreads();
    for (int p = t; p < 21*25; p += 256) {
        int by = p / 25, ty = p % 25;
        int base = (int)(by * (1200.0 / 42.0));
        int y = (ty + 4 + base) << 1;
        if (y < HH) rawr[y] = 1;
    }
    for (int p = t; p < 21*40; p += 256) {
        int bx = p / 40, tx = p % 40;
        int base = (int)(bx * (1920.0 / 42.0));
        int x = (tx + 5 + base) << 1;
        if (x < WW) rawc[x] = 1;
    }
    __syncthreads();
    for (int i = t; i < HH; i += 256) {
        int iy = i * (HH - 4) / HH;
        if (rawr[iy + 4]) { int pos = atomicAdd(s_nr, 1); rowlist[pos] = (short)i; }
    }
    for (int i = t; i < WW; i += 256) {
        int ix = i * (WW - 4) / WW;
        unsigned char v = rawc[ix + 4];
        colf[i] = v;
        if (v) atomicAdd(s_nc, 1);
    }
    __syncthreads();
}

// K0: zero accumulator state (replaces hipMemsetAsync — the 62us fill anomaly)
__global__ void k_zero(unsigned int* ws) {
    int t = threadIdx.x;
    for (int i = t; i < ZERO_U32; i += 256) ws[i] = 0u;
}

// K1: coarse 4096-bin histogram over selected pixels, LDS-privatized
__global__ void k_coarse(const float* __restrict__ img, unsigned int* coarse) {
    __shared__ unsigned char rawr[HH];
    __shared__ unsigned char rawc[WW];
    __shared__ unsigned char colf[WW];
    __shared__ short rowlist[HH];
    __shared__ int s_nr, s_nc;
    __shared__ unsigned int lh[4096];
    int t = threadIdx.x;
    for (int i = t; i < 4096; i += 256) lh[i] = 0;
    build_masks(rawr, rawc, colf, rowlist, &s_nr, &s_nc);  // has trailing sync
    int nr = s_nr;
    int total = nr * WW;
    int stride = gridDim.x * 256;
    for (int p = blockIdx.x * 256 + t; p < total; p += stride) {
        int r = p / WW, c = p - r * WW;
        if (!colf[c]) continue;
        int q = merged_q(img, (int)rowlist[r] * WW + c);
        atomicAdd(&lh[q >> 8], 1u);
    }
    __syncthreads();
    for (int i = t; i < 4096; i += 256) {
        unsigned int v = lh[i];
        if (v) atomicAdd(&coarse[i], v);
    }
}

// K2: per-block coarse prefix-scan -> (T,kprime); fine 256-bin histogram in bin T
__global__ void k_fine(const float* __restrict__ img,
                       const unsigned int* __restrict__ coarse,
                       unsigned int* fine, int* ints) {
    __shared__ unsigned char rawr[HH];
    __shared__ unsigned char rawc[WW];
    __shared__ unsigned char colf[WW];
    __shared__ short rowlist[HH];
    __shared__ int s_nr, s_nc;
    __shared__ unsigned int csum[256];
    __shared__ unsigned int lfine[256];
    __shared__ int sT, skp;
    int t = threadIdx.x;
    lfine[t] = 0;
    build_masks(rawr, rawc, colf, rowlist, &s_nr, &s_nc);
    int nr = s_nr, nc = s_nc;
    long long n = (long long)nr * (long long)nc;
    unsigned int k = (unsigned int)((n >> 1) < 1 ? 1 : (n >> 1));

    unsigned int mybins[16];
    unsigned int mysum = 0;
    #pragma unroll
    for (int i = 0; i < 16; i++) { mybins[i] = coarse[t*16 + i]; mysum += mybins[i]; }
    csum[t] = mysum;
    __syncthreads();
    for (int off = 1; off < 256; off <<= 1) {
        unsigned int v = (t >= off) ? csum[t - off] : 0u;
        __syncthreads();
        csum[t] += v;
        __syncthreads();
    }
    unsigned int incl = csum[t], excl = incl - mysum;
    if (excl < k && k <= incl) {
        unsigned int cum = excl;
        #pragma unroll
        for (int i = 0; i < 16; i++) {
            if (cum + mybins[i] >= k) { sT = t*16 + i; skp = (int)(k - cum); break; }
            cum += mybins[i];
        }
    }
    __syncthreads();
    int T = sT;
    if (t == 0 && blockIdx.x == 0) { ints[0] = sT; ints[1] = skp; }

    int total = nr * WW;
    int stride = gridDim.x * 256;
    for (int p = blockIdx.x * 256 + t; p < total; p += stride) {
        int r = p / WW, c = p - r * WW;
        if (!colf[c]) continue;
        int q = merged_q(img, (int)rowlist[r] * WW + c);
        if ((q >> 8) == T) atomicAdd(&lfine[q & 255], 1u);
    }
    __syncthreads();
    if (lfine[t]) atomicAdd(&fine[t], lfine[t]);
}

// K3: crop-0 histogram; per-block parallel median-select from fine
#define CROP_PPT 8
__global__ void k_crophist(const float* __restrict__ img,
                           const unsigned int* __restrict__ fine,
                           const int* __restrict__ ints,
                           unsigned int* hist) {
    __shared__ unsigned int lh[256];
    __shared__ unsigned int fsum[256];
    __shared__ float s_scale;
    int t = threadIdx.x;
    lh[t] = 0;
    unsigned int fv = fine[t];
    fsum[t] = fv;
    __syncthreads();
    for (int off = 1; off < 256; off <<= 1) {
        unsigned int v = (t >= off) ? fsum[t - off] : 0u;
        __syncthreads();
        fsum[t] += v;
        __syncthreads();
    }
    unsigned int incl = fsum[t], excl = incl - fv;
    unsigned int kp = (unsigned int)ints[1];
    int T = ints[0];
    if (excl < kp && kp <= incl) {   // exactly one thread (kp <= sum(fine) by construction)
        float median = fmaxf((float)(T*256 + t) * (1.0f/256.0f), MINC);
        s_scale = 1.0f / (1024.0f * median);
    }
    __syncthreads();
    float scale = s_scale;
    int base = blockIdx.x * (256*CROP_PPT);
    for (int i = 0; i < CROP_PPT; i++) {
        int p = base + i*256 + t;
        if (p < CROP_N) {
            int pr = p / 960;
            int py = 1 + 2*pr;
            int px = 2*(p - pr*960);
            int idx = py * WW + px;
            float low  = rintf(img[idx] * 4095.0f);
            float mid  = rintf(img[idx + HW] * 4095.0f);
            float high = rintf(img[idx + 2*HW] * 4095.0f);
            float v = merge3(low, mid, high);
            float mv = fminf(v * scale, 1.0f);
            mv = fmaxf(mv, MINC);
            float tt = (LOGMC - logf(mv)) / LOGMC;
            int b = (int)(tt * 256.0f);
            if (b < 0) b = 0;
            if (b > 255) b = 255;
            atomicAdd(&lh[b], 1u);
        }
    }
    __syncthreads();
    if (lh[t]) atomicAdd(&hist[t], lh[t]);
}

// L1+L2 fused: a1 (128x64) computed into LDS per block, then L2 -> a2 (256x16)
__global__ void k_l12(const unsigned int* __restrict__ hist,
                      const float* __restrict__ w1, const float* __restrict__ b1,
                      const float* __restrict__ w2, const float* __restrict__ b2,
                      float* a2) {
    __shared__ float sa1[8192];
    int t = threadIdx.x;
    for (int j = t; j < 8192; j += 256) {
        int oc = j >> 6, r = j & 63;
        float acc = b1[oc];
        for (int kh = 0; kh < 4; kh++) {
            float h = ((float)hist[4*r + kh] / 576000.0f) * 256.0f;
            acc += h * w1[oc*4 + kh];
        }
        sa1[j] = fmaxf(acc, 0.0f);
    }
    __syncthreads();
    int o = blockIdx.x * 256 + t;     // 0..4095
    int oc = o >> 4, r = o & 15;
    float acc = b2[oc];
    const float* wp = w2 + oc*128*4;
    for (int ic = 0; ic < 128; ic++) {
        const float* ap = sa1 + ic*64 + 4*r;
        acc += ap[0]*wp[ic*4+0] + ap[1]*wp[ic*4+1] + ap[2]*wp[ic*4+2] + ap[3]*wp[ic*4+3];
    }
    a2[o] = fmaxf(acc, 0.0f);
}

// L3: 512 blocks (one per oc); a2 staged in LDS; 4 outputs/block
__global__ void k_l3(const float* __restrict__ a2, const float* __restrict__ w3,
                     const float* __restrict__ b3, float* a3) {
    __shared__ float sa2[4096];
    int t = threadIdx.x;
    int oc = blockIdx.x;
    for (int i = t; i < 4096; i += 256) sa2[i] = a2[i];
    __syncthreads();
    int r = t >> 6, lane = t & 63;
    const float* wp = w3 + oc*1024;
    float p = 0.0f;
    for (int ii = 0; ii < 4; ii++) {
        int ic = lane + 64*ii;
        const float* ap = sa2 + ic*16 + 4*r;
        const float* w = wp + ic*4;
        p += ap[0]*w[0] + ap[1]*w[1] + ap[2]*w[2] + ap[3]*w[3];
    }
    for (int off = 32; off > 0; off >>= 1) p += __shfl_down(p, off, 64);
    if (lane == 0) a3[oc*4 + r] = fmaxf(p + b3[oc], 0.0f);
}

// L4 (1024 blocks, one oc each) + last-block L5+L6 epilogue
__global__ void k_l4(const float* __restrict__ a3, const float* __restrict__ w4,
                     const float* __restrict__ b4, float* a4,
                     const float* __restrict__ w5, const float* __restrict__ b5,
                     const float* __restrict__ w6, const float* __restrict__ b6,
                     int* done, float* out) {
    __shared__ float red[4];
    __shared__ int s_last;
    __shared__ float sa5[16];
    int t = threadIdx.x;
    int oc = blockIdx.x;
    const float* wp = w4 + oc*2048;
    float p = 0.0f;
    for (int i = 0; i < 8; i++) {
        int m = t + 256*i;
        p += a3[m] * wp[m];
    }
    for (int off = 32; off > 0; off >>= 1) p += __shfl_down(p, off, 64);
    int lane = t & 63;
    if (lane == 0) red[t >> 6] = p;
    __syncthreads();
    if (t == 0) {
        a4[oc] = fmaxf(red[0]+red[1]+red[2]+red[3] + b4[oc], 0.0f);
        __threadfence();                       // release a4[oc] device-wide
        int v = atomicAdd(done, 1);            // device-scope
        s_last = (v == (int)gridDim.x - 1) ? 1 : 0;
    }
    __syncthreads();
    if (!s_last) return;
    __threadfence();                           // acquire: all a4 visible
    // L5: 4 waves x 4 outputs
    int w = t >> 6;
    for (int o = w; o < 16; o += 4) {
        const float* wq = w5 + o*1024;
        float q = 0.0f;
        for (int i = 0; i < 16; i++) {
            int ic = lane + 64*i;
            q += a4[ic] * wq[ic];
        }
        for (int off = 32; off > 0; off >>= 1) q += __shfl_down(q, off, 64);
        if (lane == 0) sa5[o] = fmaxf(q + b5[o], 0.0f);
    }
    __syncthreads();
    if (t == 0) {
        float o = b6[0];
        for (int ic = 0; ic < 16; ic++) o += sa5[ic] * w6[ic];
        float s = 1.0f / (1.0f + expf(-3.0f * o));
        float y = 2.0f * (s - 0.5f) * 1.3862943611198906f;  // log(4)
        out[0] = expf(y);
    }
}

extern "C" void kernel_launch(void* const* d_in, const int* in_sizes, int n_in,
                              void* d_out, int out_size, void* d_ws, size_t ws_size,
                              hipStream_t stream) {
    const float* img = (const float*)d_in[0];   // (4,3,1200,1920) f32 — only batch 0 matters
    const float* w1 = (const float*)d_in[1];
    const float* b1 = (const float*)d_in[2];
    const float* w2 = (const float*)d_in[3];
    const float* b2 = (const float*)d_in[4];
    const float* w3 = (const float*)d_in[5];
    const float* b3 = (const float*)d_in[6];
    const float* w4 = (const float*)d_in[7];
    const float* b4 = (const float*)d_in[8];
    const float* w5 = (const float*)d_in[9];
    const float* b5 = (const float*)d_in[10];
    const float* w6 = (const float*)d_in[11];
    const float* b6 = (const float*)d_in[12];
    float* out = (float*)d_out;

    char* ws = (char*)d_ws;
    unsigned int* coarse = (unsigned int*)(ws + O_COARSE);
    unsigned int* fine   = (unsigned int*)(ws + O_FINE);
    unsigned int* hist   = (unsigned int*)(ws + O_HIST);
    int* ints   = (int*)(ws + O_INTS);
    float* a2 = (float*)(ws + O_A2);
    float* a3 = (float*)(ws + O_A3);
    float* a4 = (float*)(ws + O_A4);
    int* done = ints + 2;

    k_zero<<<1, 256, 0, stream>>>((unsigned int*)ws);
    k_coarse<<<512, 256, 0, stream>>>(img, coarse);
    k_fine<<<512, 256, 0, stream>>>(img, coarse, fine, ints);
    k_crophist<<<(CROP_N + 256*CROP_PPT - 1)/(256*CROP_PPT), 256, 0, stream>>>(img, fine, ints, hist);
    k_l12<<<16, 256, 0, stream>>>(hist, w1, b1, w2, b2, a2);
    k_l3<<<512, 256, 0, stream>>>(a2, w3, b3, a3);
    k_l4<<<1024, 256, 0, stream>>>(a3, w4, b4, a4, w5, b5, w6, b6, done, out);
}

// Round 4
// 90.516 us; speedup vs baseline: 1.0874x; 1.0874x over previous
//
#include <hip/hip_runtime.h>

#define HH 1200
#define WW 1920
#define HW (HH*WW)
#define MINC (1.0f/1048575.0f)
#define LOGMC (-13.862942657524135f)
#define CROP_N 576000   // 600 rows (1,3,..,1199) x 960 cols (0,2,..,1918)

// ---- workspace layout (bytes) ----
#define O_COARSE 0          // u32[4096]
#define O_FINE   16384      // u32[256]
#define O_HIST   17408      // u32[256]
#define O_INTS   18432      // i32[8]: 0=T 1=kprime 2=done 3=nr 4=nc
#define O_ROWIDX 18464      // i32[600]
#define O_COLIDX 20896      // i32[960]
#define O_A2     24736      // f32[4096]
#define O_A3     41120      // f32[2048]
#define O_A4     49312      // f32[1024]
#define ZERO_U32 4616       // coarse+fine+hist+ints zeroed by k_setup

__device__ __forceinline__ float merge3(float low, float mid, float high) {
    float lm = (mid == 4095.0f) ? low : 0.0f;
    float hm = (mid <= 255.0f) ? high : 0.0f;
    float mm = (mid >= 256.0f && mid <= 4094.0f) ? mid : 0.0f;
    return hm * (1.0f/256.0f) + mm * (1.0f/16.0f) + lm;
}

__device__ __forceinline__ int merged_q(const float* __restrict__ img, int idx) {
    float low  = rintf(img[idx] * 4095.0f);
    float mid  = rintf(img[idx + HW] * 4095.0f);
    float high = rintf(img[idx + 2*HW] * 4095.0f);
    float v = merge3(low, mid, high);
    return __float2int_rn(v * 256.0f);   // exact: v is a multiple of 1/256
}

// K1: zero accumulator state + build compacted row/col index lists (1 block).
// List order is irrelevant (histogram/median over a multiset).
__global__ void k_setup(unsigned int* wsu, int* rowidx, int* colidx, int* ints) {
    __shared__ unsigned char rmask[HH];
    __shared__ unsigned char cmask[WW];
    __shared__ int s_nr, s_nc;
    int t = threadIdx.x;
    for (int i = t; i < ZERO_U32; i += 256) wsu[i] = 0u;   // coarse+fine+hist+ints
    for (int i = t; i < HH; i += 256) rmask[i] = 0;
    for (int i = t; i < WW; i += 256) cmask[i] = 0;
    if (t == 0) { s_nr = 0; s_nc = 0; }
    __syncthreads();
    for (int p = t; p < 21*25; p += 256) {
        int by = p / 25, ty = p % 25;
        int base = (int)(by * (1200.0 / 42.0));
        int y = (ty + 4 + base) << 1;
        if (y < HH) rmask[y] = 1;
    }
    for (int p = t; p < 21*40; p += 256) {
        int bx = p / 40, tx = p % 40;
        int base = (int)(bx * (1920.0 / 42.0));
        int x = (tx + 5 + base) << 1;
        if (x < WW) cmask[x] = 1;
    }
    __syncthreads();
    for (int i = t; i < HH; i += 256) {
        int iy = i * (HH - 4) / HH;
        if (rmask[iy + 4]) { int pos = atomicAdd(&s_nr, 1); rowidx[pos] = i; }
    }
    for (int i = t; i < WW; i += 256) {
        int ix = i * (WW - 4) / WW;
        if (cmask[ix + 4]) { int pos = atomicAdd(&s_nc, 1); colidx[pos] = i; }
    }
    __syncthreads();
    if (t == 0) { ints[3] = s_nr; ints[4] = s_nc; }
}

// K2: coarse 4096-bin histogram over selected pixels, LDS-privatized
__global__ void k_coarse(const float* __restrict__ img,
                         const int* __restrict__ rowidx,
                         const int* __restrict__ colidx,
                         const int* __restrict__ ints,
                         unsigned int* coarse) {
    __shared__ unsigned int lh[4096];
    int t = threadIdx.x;
    for (int i = t; i < 4096; i += 256) lh[i] = 0;
    __syncthreads();
    int nr = ints[3], nc = ints[4];
    int total = nr * nc;
    int stride = gridDim.x * 256;
    for (int p = blockIdx.x * 256 + t; p < total; p += stride) {
        int r = p / nc, c = p - r * nc;
        int q = merged_q(img, rowidx[r] * WW + colidx[c]);
        atomicAdd(&lh[q >> 8], 1u);
    }
    __syncthreads();
    for (int i = t; i < 4096; i += 256) {
        unsigned int v = lh[i];
        if (v) atomicAdd(&coarse[i], v);
    }
}

// K3: per-block coarse prefix-scan -> (T,kprime); fine 256-bin histogram in bin T
__global__ void k_fine(const float* __restrict__ img,
                       const int* __restrict__ rowidx,
                       const int* __restrict__ colidx,
                       const unsigned int* __restrict__ coarse,
                       unsigned int* fine, int* ints) {
    __shared__ unsigned int csum[256];
    __shared__ unsigned int lfine[256];
    __shared__ int sT, skp;
    int t = threadIdx.x;
    lfine[t] = 0;
    int nr = ints[3], nc = ints[4];
    long long n = (long long)nr * (long long)nc;
    unsigned int k = (unsigned int)((n >> 1) < 1 ? 1 : (n >> 1));

    unsigned int mybins[16];
    unsigned int mysum = 0;
    #pragma unroll
    for (int i = 0; i < 16; i++) { mybins[i] = coarse[t*16 + i]; mysum += mybins[i]; }
    csum[t] = mysum;
    __syncthreads();
    for (int off = 1; off < 256; off <<= 1) {
        unsigned int v = (t >= off) ? csum[t - off] : 0u;
        __syncthreads();
        csum[t] += v;
        __syncthreads();
    }
    unsigned int incl = csum[t], excl = incl - mysum;
    if (excl < k && k <= incl) {
        unsigned int cum = excl;
        #pragma unroll
        for (int i = 0; i < 16; i++) {
            if (cum + mybins[i] >= k) { sT = t*16 + i; skp = (int)(k - cum); break; }
            cum += mybins[i];
        }
    }
    __syncthreads();
    int T = sT;
    if (t == 0 && blockIdx.x == 0) { ints[0] = sT; ints[1] = skp; }

    int total = nr * nc;
    int stride = gridDim.x * 256;
    for (int p = blockIdx.x * 256 + t; p < total; p += stride) {
        int r = p / nc, c = p - r * nc;
        int q = merged_q(img, rowidx[r] * WW + colidx[c]);
        if ((q >> 8) == T) atomicAdd(&lfine[q & 255], 1u);
    }
    __syncthreads();
    if (lfine[t]) atomicAdd(&fine[t], lfine[t]);
}

// K4: crop-0 histogram; per-block parallel median-select from fine
#define CROP_PPT 8
__global__ void k_crophist(const float* __restrict__ img,
                           const unsigned int* __restrict__ fine,
                           const int* __restrict__ ints,
                           unsigned int* hist) {
    __shared__ unsigned int lh[256];
    __shared__ unsigned int fsum[256];
    __shared__ float s_scale;
    int t = threadIdx.x;
    lh[t] = 0;
    unsigned int fv = fine[t];
    fsum[t] = fv;
    __syncthreads();
    for (int off = 1; off < 256; off <<= 1) {
        unsigned int v = (t >= off) ? fsum[t - off] : 0u;
        __syncthreads();
        fsum[t] += v;
        __syncthreads();
    }
    unsigned int incl = fsum[t], excl = incl - fv;
    unsigned int kp = (unsigned int)ints[1];
    int T = ints[0];
    if (excl < kp && kp <= incl) {   // exactly one thread
        float median = fmaxf((float)(T*256 + t) * (1.0f/256.0f), MINC);
        s_scale = 1.0f / (1024.0f * median);
    }
    __syncthreads();
    float scale = s_scale;
    int base = blockIdx.x * (256*CROP_PPT);
    for (int i = 0; i < CROP_PPT; i++) {
        int p = base + i*256 + t;
        if (p < CROP_N) {
            int pr = p / 960;
            int py = 1 + 2*pr;
            int px = 2*(p - pr*960);
            int idx = py * WW + px;
            float low  = rintf(img[idx] * 4095.0f);
            float mid  = rintf(img[idx + HW] * 4095.0f);
            float high = rintf(img[idx + 2*HW] * 4095.0f);
            float v = merge3(low, mid, high);
            float mv = fminf(v * scale, 1.0f);
            mv = fmaxf(mv, MINC);
            float tt = (LOGMC - logf(mv)) / LOGMC;
            int b = (int)(tt * 256.0f);
            if (b < 0) b = 0;
            if (b > 255) b = 255;
            atomicAdd(&lh[b], 1u);
        }
    }
    __syncthreads();
    if (lh[t]) atomicAdd(&hist[t], lh[t]);
}

// L1+L2 fused: a1 (128x64) computed into LDS per block, then L2 -> a2 (256x16)
__global__ void k_l12(const unsigned int* __restrict__ hist,
                      const float* __restrict__ w1, const float* __restrict__ b1,
                      const float* __restrict__ w2, const float* __restrict__ b2,
                      float* a2) {
    __shared__ float sa1[8192];
    int t = threadIdx.x;
    for (int j = t; j < 8192; j += 256) {
        int oc = j >> 6, r = j & 63;
        float acc = b1[oc];
        for (int kh = 0; kh < 4; kh++) {
            float h = ((float)hist[4*r + kh] / 576000.0f) * 256.0f;
            acc += h * w1[oc*4 + kh];
        }
        sa1[j] = fmaxf(acc, 0.0f);
    }
    __syncthreads();
    int o = blockIdx.x * 256 + t;     // 0..4095
    int oc = o >> 4, r = o & 15;
    float acc = b2[oc];
    const float* wp = w2 + oc*128*4;
    for (int ic = 0; ic < 128; ic++) {
        const float* ap = sa1 + ic*64 + 4*r;
        acc += ap[0]*wp[ic*4+0] + ap[1]*wp[ic*4+1] + ap[2]*wp[ic*4+2] + ap[3]*wp[ic*4+3];
    }
    a2[o] = fmaxf(acc, 0.0f);
}

// L3: 512 blocks (one per oc); a2 staged in LDS; 4 outputs/block
__global__ void k_l3(const float* __restrict__ a2, const float* __restrict__ w3,
                     const float* __restrict__ b3, float* a3) {
    __shared__ float sa2[4096];
    int t = threadIdx.x;
    int oc = blockIdx.x;
    for (int i = t; i < 4096; i += 256) sa2[i] = a2[i];
    __syncthreads();
    int r = t >> 6, lane = t & 63;
    const float* wp = w3 + oc*1024;
    float p = 0.0f;
    for (int ii = 0; ii < 4; ii++) {
        int ic = lane + 64*ii;
        const float* ap = sa2 + ic*16 + 4*r;
        const float* w = wp + ic*4;
        p += ap[0]*w[0] + ap[1]*w[1] + ap[2]*w[2] + ap[3]*w[3];
    }
    for (int off = 32; off > 0; off >>= 1) p += __shfl_down(p, off, 64);
    if (lane == 0) a3[oc*4 + r] = fmaxf(p + b3[oc], 0.0f);
}

// L4 (1024 blocks, one oc each) + last-block L5+L6 epilogue
__global__ void k_l4(const float* __restrict__ a3, const float* __restrict__ w4,
                     const float* __restrict__ b4, float* a4,
                     const float* __restrict__ w5, const float* __restrict__ b5,
                     const float* __restrict__ w6, const float* __restrict__ b6,
                     int* done, float* out) {
    __shared__ float red[4];
    __shared__ int s_last;
    __shared__ float sa5[16];
    int t = threadIdx.x;
    int oc = blockIdx.x;
    const float* wp = w4 + oc*2048;
    float p = 0.0f;
    for (int i = 0; i < 8; i++) {
        int m = t + 256*i;
        p += a3[m] * wp[m];
    }
    for (int off = 32; off > 0; off >>= 1) p += __shfl_down(p, off, 64);
    int lane = t & 63;
    if (lane == 0) red[t >> 6] = p;
    __syncthreads();
    if (t == 0) {
        a4[oc] = fmaxf(red[0]+red[1]+red[2]+red[3] + b4[oc], 0.0f);
        __threadfence();                       // release a4[oc] device-wide
        int v = atomicAdd(done, 1);            // device-scope
        s_last = (v == (int)gridDim.x - 1) ? 1 : 0;
    }
    __syncthreads();
    if (!s_last) return;
    __threadfence();                           // acquire: all a4 visible
    int w = t >> 6;
    for (int o = w; o < 16; o += 4) {
        const float* wq = w5 + o*1024;
        float q = 0.0f;
        for (int i = 0; i < 16; i++) {
            int ic = lane + 64*i;
            q += a4[ic] * wq[ic];
        }
        for (int off = 32; off > 0; off >>= 1) q += __shfl_down(q, off, 64);
        if (lane == 0) sa5[o] = fmaxf(q + b5[o], 0.0f);
    }
    __syncthreads();
    if (t == 0) {
        float o = b6[0];
        for (int ic = 0; ic < 16; ic++) o += sa5[ic] * w6[ic];
        float s = 1.0f / (1.0f + expf(-3.0f * o));
        float y = 2.0f * (s - 0.5f) * 1.3862943611198906f;  // log(4)
        out[0] = expf(y);
    }
}

extern "C" void kernel_launch(void* const* d_in, const int* in_sizes, int n_in,
                              void* d_out, int out_size, void* d_ws, size_t ws_size,
                              hipStream_t stream) {
    const float* img = (const float*)d_in[0];   // (4,3,1200,1920) f32 — only batch 0 matters
    const float* w1 = (const float*)d_in[1];
    const float* b1 = (const float*)d_in[2];
    const float* w2 = (const float*)d_in[3];
    const float* b2 = (const float*)d_in[4];
    const float* w3 = (const float*)d_in[5];
    const float* b3 = (const float*)d_in[6];
    const float* w4 = (const float*)d_in[7];
    const float* b4 = (const float*)d_in[8];
    const float* w5 = (const float*)d_in[9];
    const float* b5 = (const float*)d_in[10];
    const float* w6 = (const float*)d_in[11];
    const float* b6 = (const float*)d_in[12];
    float* out = (float*)d_out;

    char* ws = (char*)d_ws;
    unsigned int* coarse = (unsigned int*)(ws + O_COARSE);
    unsigned int* fine   = (unsigned int*)(ws + O_FINE);
    unsigned int* hist   = (unsigned int*)(ws + O_HIST);
    int* ints   = (int*)(ws + O_INTS);
    int* rowidx = (int*)(ws + O_ROWIDX);
    int* colidx = (int*)(ws + O_COLIDX);
    float* a2 = (float*)(ws + O_A2);
    float* a3 = (float*)(ws + O_A3);
    float* a4 = (float*)(ws + O_A4);
    int* done = ints + 2;

    k_setup<<<1, 256, 0, stream>>>((unsigned int*)ws, rowidx, colidx, ints);
    k_coarse<<<128, 256, 0, stream>>>(img, rowidx, colidx, ints, coarse);
    k_fine<<<128, 256, 0, stream>>>(img, rowidx, colidx, coarse, fine, ints);
    k_crophist<<<(CROP_N + 256*CROP_PPT - 1)/(256*CROP_PPT), 256, 0, stream>>>(img, fine, ints, hist);
    k_l12<<<16, 256, 0, stream>>>(hist, w1, b1, w2, b2, a2);
    k_l3<<<512, 256, 0, stream>>>(a2, w3, b3, a3);
    k_l4<<<1024, 256, 0, stream>>>(a3, w4, b4, a4, w5, b5, w6, b6, done, out);
}

// Round 5
// 65.711 us; speedup vs baseline: 1.4979x; 1.3775x over previous
//
#include <hip/hip_runtime.h>

#define HH 1200
#define WW 1920
#define HW (HH*WW)
#define MINC (1.0f/1048575.0f)
#define LOGMC (-13.862942657524135f)
#define CROP_N 576000   // 600 rows (1,3,..,1199) x 960 cols (0,2,..,1918)

// ---- workspace layout (bytes) ----
#define O_COARSE 0          // u32[4096]
#define O_FINE   16384      // u32[256]
#define O_HIST   17408      // u32[256]
#define O_INTS   18432      // i32[8]: 0=T 1=kprime 3=nr 4=nc
#define O_ROWIDX 18464      // i32[600]
#define O_COLIDX 20896      // i32[960]
#define O_A2     24736      // f32[4096]
#define O_A3     41120      // f32[2048]
#define O_A4     49312      // f32[1024]
#define O_A5     53408      // f32[16]
#define ZERO_U32 4616       // coarse+fine+hist+ints zeroed by k_setup

__device__ __forceinline__ float merge3(float low, float mid, float high) {
    float lm = (mid == 4095.0f) ? low : 0.0f;
    float hm = (mid <= 255.0f) ? high : 0.0f;
    float mm = (mid >= 256.0f && mid <= 4094.0f) ? mid : 0.0f;
    return hm * (1.0f/256.0f) + mm * (1.0f/16.0f) + lm;
}

__device__ __forceinline__ int merged_q(const float* __restrict__ img, int idx) {
    float low  = rintf(img[idx] * 4095.0f);
    float mid  = rintf(img[idx + HW] * 4095.0f);
    float high = rintf(img[idx + 2*HW] * 4095.0f);
    float v = merge3(low, mid, high);
    return __float2int_rn(v * 256.0f);   // exact: v is a multiple of 1/256
}

// K1: zero accumulator state + build compacted row/col index lists (1 block).
// List order is irrelevant (histogram/median over a multiset).
__global__ void k_setup(unsigned int* wsu, int* rowidx, int* colidx, int* ints) {
    __shared__ unsigned char rmask[HH];
    __shared__ unsigned char cmask[WW];
    __shared__ int s_nr, s_nc;
    int t = threadIdx.x;
    for (int i = t; i < ZERO_U32; i += 256) wsu[i] = 0u;   // coarse+fine+hist+ints
    for (int i = t; i < HH; i += 256) rmask[i] = 0;
    for (int i = t; i < WW; i += 256) cmask[i] = 0;
    if (t == 0) { s_nr = 0; s_nc = 0; }
    __syncthreads();
    for (int p = t; p < 21*25; p += 256) {
        int by = p / 25, ty = p % 25;
        int base = (int)(by * (1200.0 / 42.0));
        int y = (ty + 4 + base) << 1;
        if (y < HH) rmask[y] = 1;
    }
    for (int p = t; p < 21*40; p += 256) {
        int bx = p / 40, tx = p % 40;
        int base = (int)(bx * (1920.0 / 42.0));
        int x = (tx + 5 + base) << 1;
        if (x < WW) cmask[x] = 1;
    }
    __syncthreads();
    for (int i = t; i < HH; i += 256) {
        int iy = i * (HH - 4) / HH;
        if (rmask[iy + 4]) { int pos = atomicAdd(&s_nr, 1); rowidx[pos] = i; }
    }
    for (int i = t; i < WW; i += 256) {
        int ix = i * (WW - 4) / WW;
        if (cmask[ix + 4]) { int pos = atomicAdd(&s_nc, 1); colidx[pos] = i; }
    }
    __syncthreads();
    if (t == 0) { ints[3] = s_nr; ints[4] = s_nc; }
}

// K2: coarse 4096-bin histogram over selected pixels, LDS-privatized
__global__ void k_coarse(const float* __restrict__ img,
                         const int* __restrict__ rowidx,
                         const int* __restrict__ colidx,
                         const int* __restrict__ ints,
                         unsigned int* coarse) {
    __shared__ unsigned int lh[4096];
    int t = threadIdx.x;
    for (int i = t; i < 4096; i += 256) lh[i] = 0;
    __syncthreads();
    int nr = ints[3], nc = ints[4];
    int total = nr * nc;
    int stride = gridDim.x * 256;
    for (int p = blockIdx.x * 256 + t; p < total; p += stride) {
        int r = p / nc, c = p - r * nc;
        int q = merged_q(img, rowidx[r] * WW + colidx[c]);
        atomicAdd(&lh[q >> 8], 1u);
    }
    __syncthreads();
    for (int i = t; i < 4096; i += 256) {
        unsigned int v = lh[i];
        if (v) atomicAdd(&coarse[i], v);
    }
}

// K3: per-block coarse prefix-scan -> (T,kprime); fine 256-bin histogram in bin T
__global__ void k_fine(const float* __restrict__ img,
                       const int* __restrict__ rowidx,
                       const int* __restrict__ colidx,
                       const unsigned int* __restrict__ coarse,
                       unsigned int* fine, int* ints) {
    __shared__ unsigned int csum[256];
    __shared__ unsigned int lfine[256];
    __shared__ int sT, skp;
    int t = threadIdx.x;
    lfine[t] = 0;
    int nr = ints[3], nc = ints[4];
    long long n = (long long)nr * (long long)nc;
    unsigned int k = (unsigned int)((n >> 1) < 1 ? 1 : (n >> 1));

    unsigned int mybins[16];
    unsigned int mysum = 0;
    #pragma unroll
    for (int i = 0; i < 16; i++) { mybins[i] = coarse[t*16 + i]; mysum += mybins[i]; }
    csum[t] = mysum;
    __syncthreads();
    for (int off = 1; off < 256; off <<= 1) {
        unsigned int v = (t >= off) ? csum[t - off] : 0u;
        __syncthreads();
        csum[t] += v;
        __syncthreads();
    }
    unsigned int incl = csum[t], excl = incl - mysum;
    if (excl < k && k <= incl) {
        unsigned int cum = excl;
        #pragma unroll
        for (int i = 0; i < 16; i++) {
            if (cum + mybins[i] >= k) { sT = t*16 + i; skp = (int)(k - cum); break; }
            cum += mybins[i];
        }
    }
    __syncthreads();
    int T = sT;
    if (t == 0 && blockIdx.x == 0) { ints[0] = sT; ints[1] = skp; }

    int total = nr * nc;
    int stride = gridDim.x * 256;
    for (int p = blockIdx.x * 256 + t; p < total; p += stride) {
        int r = p / nc, c = p - r * nc;
        int q = merged_q(img, rowidx[r] * WW + colidx[c]);
        if ((q >> 8) == T) atomicAdd(&lfine[q & 255], 1u);
    }
    __syncthreads();
    if (lfine[t]) atomicAdd(&fine[t], lfine[t]);
}

// K4: crop-0 histogram; per-block parallel median-select from fine
#define CROP_PPT 8
__global__ void k_crophist(const float* __restrict__ img,
                           const unsigned int* __restrict__ fine,
                           const int* __restrict__ ints,
                           unsigned int* hist) {
    __shared__ unsigned int lh[256];
    __shared__ unsigned int fsum[256];
    __shared__ float s_scale;
    int t = threadIdx.x;
    lh[t] = 0;
    unsigned int fv = fine[t];
    fsum[t] = fv;
    __syncthreads();
    for (int off = 1; off < 256; off <<= 1) {
        unsigned int v = (t >= off) ? fsum[t - off] : 0u;
        __syncthreads();
        fsum[t] += v;
        __syncthreads();
    }
    unsigned int incl = fsum[t], excl = incl - fv;
    unsigned int kp = (unsigned int)ints[1];
    int T = ints[0];
    if (excl < kp && kp <= incl) {   // exactly one thread
        float median = fmaxf((float)(T*256 + t) * (1.0f/256.0f), MINC);
        s_scale = 1.0f / (1024.0f * median);
    }
    __syncthreads();
    float scale = s_scale;
    int base = blockIdx.x * (256*CROP_PPT);
    for (int i = 0; i < CROP_PPT; i++) {
        int p = base + i*256 + t;
        if (p < CROP_N) {
            int pr = p / 960;
            int py = 1 + 2*pr;
            int px = 2*(p - pr*960);
            int idx = py * WW + px;
            float low  = rintf(img[idx] * 4095.0f);
            float mid  = rintf(img[idx + HW] * 4095.0f);
            float high = rintf(img[idx + 2*HW] * 4095.0f);
            float v = merge3(low, mid, high);
            float mv = fminf(v * scale, 1.0f);
            mv = fmaxf(mv, MINC);
            float tt = (LOGMC - logf(mv)) / LOGMC;
            int b = (int)(tt * 256.0f);
            if (b < 0) b = 0;
            if (b > 255) b = 255;
            atomicAdd(&lh[b], 1u);
        }
    }
    __syncthreads();
    if (lh[t]) atomicAdd(&hist[t], lh[t]);
}

// L1+L2 fused: a1 (128x64) computed into LDS per block, then L2 -> a2 (256x16)
__global__ void k_l12(const unsigned int* __restrict__ hist,
                      const float* __restrict__ w1, const float* __restrict__ b1,
                      const float* __restrict__ w2, const float* __restrict__ b2,
                      float* a2) {
    __shared__ float sa1[8192];
    int t = threadIdx.x;
    for (int j = t; j < 8192; j += 256) {
        int oc = j >> 6, r = j & 63;
        float acc = b1[oc];
        for (int kh = 0; kh < 4; kh++) {
            float h = ((float)hist[4*r + kh] / 576000.0f) * 256.0f;
            acc += h * w1[oc*4 + kh];
        }
        sa1[j] = fmaxf(acc, 0.0f);
    }
    __syncthreads();
    int o = blockIdx.x * 256 + t;     // 0..4095
    int oc = o >> 4, r = o & 15;
    float acc = b2[oc];
    const float* wp = w2 + oc*128*4;
    for (int ic = 0; ic < 128; ic++) {
        const float* ap = sa1 + ic*64 + 4*r;
        acc += ap[0]*wp[ic*4+0] + ap[1]*wp[ic*4+1] + ap[2]*wp[ic*4+2] + ap[3]*wp[ic*4+3];
    }
    a2[o] = fmaxf(acc, 0.0f);
}

// L3: 512 blocks (one per oc); a2 staged in LDS; 4 outputs/block
__global__ void k_l3(const float* __restrict__ a2, const float* __restrict__ w3,
                     const float* __restrict__ b3, float* a3) {
    __shared__ float sa2[4096];
    int t = threadIdx.x;
    int oc = blockIdx.x;
    for (int i = t; i < 4096; i += 256) sa2[i] = a2[i];
    __syncthreads();
    int r = t >> 6, lane = t & 63;
    const float* wp = w3 + oc*1024;
    float p = 0.0f;
    for (int ii = 0; ii < 4; ii++) {
        int ic = lane + 64*ii;
        const float* ap = sa2 + ic*16 + 4*r;
        const float* w = wp + ic*4;
        p += ap[0]*w[0] + ap[1]*w[1] + ap[2]*w[2] + ap[3]*w[3];
    }
    for (int off = 32; off > 0; off >>= 1) p += __shfl_down(p, off, 64);
    if (lane == 0) a3[oc*4 + r] = fmaxf(p + b3[oc], 0.0f);
}

// L4: 1024 blocks (one per oc), 256 threads; dot of length 2048 (no done-counter)
__global__ void k_l4(const float* __restrict__ a3, const float* __restrict__ w4,
                     const float* __restrict__ b4, float* a4) {
    __shared__ float red[4];
    int t = threadIdx.x;
    int oc = blockIdx.x;
    const float* wp = w4 + oc*2048;
    float p = 0.0f;
    for (int i = 0; i < 8; i++) {
        int m = t + 256*i;
        p += a3[m] * wp[m];
    }
    for (int off = 32; off > 0; off >>= 1) p += __shfl_down(p, off, 64);
    int lane = t & 63;
    if (lane == 0) red[t >> 6] = p;
    __syncthreads();
    if (t == 0) a4[oc] = fmaxf(red[0]+red[1]+red[2]+red[3] + b4[oc], 0.0f);
}

// L5+L6 fused: 1 block, 1024 threads (16 waves, one per L5 output) + epilogue
__global__ void k_l56(const float* __restrict__ a4,
                      const float* __restrict__ w5, const float* __restrict__ b5,
                      const float* __restrict__ w6, const float* __restrict__ b6,
                      float* out) {
    __shared__ float sa5[16];
    int t = threadIdx.x;
    int w = t >> 6, lane = t & 63;
    const float* wp = w5 + w*1024;
    float p = 0.0f;
    for (int i = 0; i < 16; i++) {
        int ic = lane + 64*i;
        p += a4[ic] * wp[ic];
    }
    for (int off = 32; off > 0; off >>= 1) p += __shfl_down(p, off, 64);
    if (lane == 0) sa5[w] = fmaxf(p + b5[w], 0.0f);
    __syncthreads();
    if (t == 0) {
        float o = b6[0];
        for (int ic = 0; ic < 16; ic++) o += sa5[ic] * w6[ic];
        float s = 1.0f / (1.0f + expf(-3.0f * o));
        float y = 2.0f * (s - 0.5f) * 1.3862943611198906f;  // log(4)
        out[0] = expf(y);
    }
}

extern "C" void kernel_launch(void* const* d_in, const int* in_sizes, int n_in,
                              void* d_out, int out_size, void* d_ws, size_t ws_size,
                              hipStream_t stream) {
    const float* img = (const float*)d_in[0];   // (4,3,1200,1920) f32 — only batch 0 matters
    const float* w1 = (const float*)d_in[1];
    const float* b1 = (const float*)d_in[2];
    const float* w2 = (const float*)d_in[3];
    const float* b2 = (const float*)d_in[4];
    const float* w3 = (const float*)d_in[5];
    const float* b3 = (const float*)d_in[6];
    const float* w4 = (const float*)d_in[7];
    const float* b4 = (const float*)d_in[8];
    const float* w5 = (const float*)d_in[9];
    const float* b5 = (const float*)d_in[10];
    const float* w6 = (const float*)d_in[11];
    const float* b6 = (const float*)d_in[12];
    float* out = (float*)d_out;

    char* ws = (char*)d_ws;
    unsigned int* coarse = (unsigned int*)(ws + O_COARSE);
    unsigned int* fine   = (unsigned int*)(ws + O_FINE);
    unsigned int* hist   = (unsigned int*)(ws + O_HIST);
    int* ints   = (int*)(ws + O_INTS);
    int* rowidx = (int*)(ws + O_ROWIDX);
    int* colidx = (int*)(ws + O_COLIDX);
    float* a2 = (float*)(ws + O_A2);
    float* a3 = (float*)(ws + O_A3);
    float* a4 = (float*)(ws + O_A4);

    k_setup<<<1, 256, 0, stream>>>((unsigned int*)ws, rowidx, colidx, ints);
    k_coarse<<<256, 256, 0, stream>>>(img, rowidx, colidx, ints, coarse);
    k_fine<<<256, 256, 0, stream>>>(img, rowidx, colidx, coarse, fine, ints);
    k_crophist<<<(CROP_N + 256*CROP_PPT - 1)/(256*CROP_PPT), 256, 0, stream>>>(img, fine, ints, hist);
    k_l12<<<16, 256, 0, stream>>>(hist, w1, b1, w2, b2, a2);
    k_l3<<<512, 256, 0, stream>>>(a2, w3, b3, a3);
    k_l4<<<1024, 256, 0, stream>>>(a3, w4, b4, a4);
    k_l56<<<1, 1024, 0, stream>>>(a4, w5, b5, w6, b6, out);
}